// Round 26
// baseline (58.627 us; speedup 1.0000x reference)
//
#include <hip/hip_runtime.h>
#include <hip/hip_fp16.h>

#define W 256
#define NA 180
#define STRIDE 65             // words per window row; compile-time, odd -> bank spread
#define NROWS 104             // worst-case rows for index=2 (<=103)
#define SALLOC (NROWS * STRIDE + 80)   // 27,360 B -> 4 blocks/CU (32-wave cap)

// Block = (a, n, cq, rh): 64 columns x one r-half (t1 taps).
// Window = bbox of its clamped taps (biased: half = px+2, row = py+1), fp16,
// fixed stride 65; un-staged cells are zero guards. Outputs via 2-way atomicAdd.

__global__ __launch_bounds__(512, 8) void radon_kernel(
    const float* __restrict__ x, const int* __restrict__ index_p,
    float* __restrict__ out)
{
    __shared__ unsigned sw[SALLOC];

    const int a = blockIdx.x;
    const int n = blockIdx.y;
    const int cq = blockIdx.z & 3;
    const int rh = blockIdx.z >> 2;
    const int tid = threadIdx.x;
    const int cl = tid & 63;         // lane = local column
    const int s = tid >> 6;          // r-chunk 0..7 (wave-uniform)

    const int index = *index_p;
    const int seg[6] = {1, 26, 51, 77, 102, 128};
    const int t0 = seg[4 - index];
    const int t1 = seg[4 - index + 1];
    const int r1lo = 128 - t1;
    const int r0lo = 128 - t0, r0hi = 127 + t0;
    const int rA = r1lo + rh * t1;   // owns r in [rA, rA+t1)

    float sa, ca;
    sincosf((float)a * 0.017453292519943295f, &sa, &ca);
    const float asa = fabsf(sa), aca = fabsf(ca);

    // ---- center+extent bbox (covers corner bbox; +0.75 fp slack) ----
    const float xcen = ((float)(cq * 64 + 32)) * (1.0f / 128.0f) - 1.0f;
    const float half_r = 0.5f * (float)(t1 - 1);
    const float rfc = (float)rA - 127.5f + half_r;
    const float ixc = fmaf(sa, rfc, fmaf(128.0f * ca, xcen, 129.5f));
    const float iyc = fmaf(ca, rfc, fmaf(-128.0f * sa, xcen, 128.5f));
    const float hx = fmaf(asa, half_r, 31.5f * aca) + 0.75f;
    const float hy = fmaf(aca, half_r, 31.5f * asa) + 0.75f;
    const float ixmin = __builtin_amdgcn_fmed3f(ixc - hx, 1.0f, 258.0f);
    const float ixmax = __builtin_amdgcn_fmed3f(ixc + hx, 1.0f, 258.0f);
    const float iymin = __builtin_amdgcn_fmed3f(iyc - hy, 0.0f, 257.0f);
    const float iymax = __builtin_amdgcn_fmed3f(iyc + hy, 0.0f, 257.0f);

    const int gx0 = ((int)ixmin) & ~1;            // even, >= 0
    const int gx1 = (int)ixmax + 1;
    const int gy0 = (int)iymin;
    int gy1 = (int)iymax + 1;
    if (gy1 - gy0 + 1 > NROWS) gy1 = gy0 + NROWS - 1;  // safety (no-op for index=2)
    const int nrows = gy1 - gy0 + 1;
    const int nw = min(((gx1 >> 1) - (gx0 >> 1)) + 2, STRIDE);  // <= 55 for index=2

    const int pylo = max(gy0 - 1, 0);
    const int pyhi = min(gy1 - 1, 255);
    const int nlr = pyhi - pylo + 1;
    const int lbase = pylo + 1 - gy0;             // 0 or 1
    const int pxlo = max(gx0 - 2, 0);             // even
    const int pxhi = min(gx1 - 2, 255);
    const int wv0 = (pxlo - gx0 + 2) >> 1;        // 0 or 1
    const int nq2 = min((pxhi - pxlo + 2) >> 1, STRIDE - wv0);  // <= 53

    // ---- guard superset zero: cols {0,1,nw-2,nw-1} x all rows; unstaged rows ----
    {
        const int i = tid;                        // 4*NROWS = 416 <= 512: one pass
        if (i < 4 * NROWS) {
            const int row = i >> 2;
            const int wsel = i & 3;
            const int w = (wsel < 2) ? wsel : (nw - 4 + wsel);
            sw[row * STRIDE + w] = 0u;
        }
        const int topcnt = nrows - lbase - nlr;   // 0..2 rows unstaged at top
        const int nz = (lbase + topcnt) * STRIDE; // <= 3*65 = 195 <= 512: one pass
        if (i < nz) {
            const int rr = i / STRIDE;            // 0..2 (const-div magic)
            const int w = i - rr * STRIDE;
            const int row = (rr < lbase) ? 0 : (nrows - topcnt + (rr - lbase));
            sw[row * STRIDE + w] = 0u;
        }
    }
    __syncthreads();

    // ---- stage valid sub-rectangle: one conditional word per (row, lane) ----
    {
        const float* __restrict__ imgp = x + (size_t)n * W * W;
        if (cl < nq2) {
            for (int lr = s; lr < nlr; lr += 8) {
                const float2 v = *(const float2*)(imgp + (pylo + lr) * W + pxlo + 2 * cl);
                const __half2 hp = __floats2half2_rn(v.x, v.y);
                sw[(lbase + lr) * STRIDE + wv0 + cl] = *(const unsigned*)&hp;
            }
        }
    }
    __syncthreads();

    // ---- tap loop (R19 body; compile-time stride, window-local base) ----
    const int c = cq * 64 + cl;
    const float xc = ((2.0f * (float)c + 1.0f) * (1.0f / 256.0f)) - 1.0f;
    const float bx = fmaf(128.0f * ca, xc, 129.5f);
    const float by = fmaf(-128.0f * sa, xc, 128.5f);
    const int wbase = -(gy0 * STRIDE + (gx0 >> 1));
    const int chunk = (t1 + 7) >> 3;
    const int rs = rA + s * chunk;
    const int re = min(rs + chunk, rA + t1);
    const int w0 = r0hi - r0lo;

    float sum0 = 0.0f, sum1 = 0.0f;
    float rf = (float)rs - 127.5f;
    #pragma unroll 4
    for (int r = rs; r < re; ++r, rf += 1.0f) {
        float ix = fmaf(sa, rf, bx);
        float iy = fmaf(ca, rf, by);
        ix = __builtin_amdgcn_fmed3f(ix, 1.0f, 258.0f);
        iy = __builtin_amdgcn_fmed3f(iy, 0.0f, 257.0f);
        const float wx = __builtin_amdgcn_fractf(ix);
        const float wy = __builtin_amdgcn_fractf(iy);
        const int x0 = (int)ix;
        const int y0 = (int)iy;
        const int wi = y0 * STRIDE + (x0 >> 1) + wbase;
        const unsigned A0 = sw[wi];
        const unsigned B0 = sw[wi + 1];
        const unsigned A1 = sw[wi + STRIDE];
        const unsigned B1 = sw[wi + STRIDE + 1];
        const int sh = (x0 & 1) << 4;
        const unsigned q0 = __builtin_amdgcn_alignbit(B0, A0, sh);
        const unsigned q1 = __builtin_amdgcn_alignbit(B1, A1, sh);
        const __half2 h0 = *(const __half2*)&q0;
        const __half2 h1 = *(const __half2*)&q1;
        const __half2 wy2 = __float2half2_rn(wy);
        const __half2 t = __hfma2(wy2, __hsub2(h1, h0), h0);
        const float tl = __low2float(t);
        const float th = __high2float(t);
        const float val = fmaf(wx, th - tl, tl);
        sum1 += val;
        if ((unsigned)(r - r0lo) <= (unsigned)w0) sum0 += val;
    }

    // ---- reduce 8 partials; alias sw as scratch ----
    __syncthreads();
    float* red = (float*)sw;                 // 4 KB of 27 KB
    red[s * 64 + cl] = sum0;
    red[512 + s * 64 + cl] = sum1;
    __syncthreads();

    if (s == 0) {
        float a0 = 0.0f, a1 = 0.0f;
        #pragma unroll
        for (int j = 0; j < 8; ++j) {
            a0 += red[j * 64 + cl];
            a1 += red[512 + j * 64 + cl];
        }
        // exactly two contributors (rh=0,1); fp add commutes -> deterministic
        atomicAdd(out + (((size_t)n * 2 + 0) * W + c) * NA + a, a0 * (1.0f / (float)(2 * t0)));
        atomicAdd(out + (((size_t)n * 2 + 1) * W + c) * NA + a, a1 * (1.0f / (float)(2 * t1)));
    }
}

extern "C" void kernel_launch(void* const* d_in, const int* in_sizes, int n_in,
                              void* d_out, int out_size, void* d_ws, size_t ws_size,
                              hipStream_t stream) {
    const float* x = (const float*)d_in[0];
    const int* index_p = (const int*)d_in[1];
    float* out = (float*)d_out;
    const int N = in_sizes[0] / (W * W); // 4

    hipMemsetAsync(d_out, 0, (size_t)out_size * sizeof(float), stream);

    dim3 grid(NA, N, 8);                 // 4 column-quarters x 2 r-halves
    radon_kernel<<<grid, 512, 0, stream>>>(x, index_p, out);
}

// Round 27
// 44.963 us; speedup vs baseline: 1.3039x; 1.3039x over previous
//
#include <hip/hip_runtime.h>
#include <hip/hip_fp16.h>

#define W 256
#define NA 180
#define SPLIT 4
#define RWORDS 145            // words per row; odd stride -> axis walks spread over banks
#define ROWBYTES 580
#define ROWS 259              // data rows 1..256 (pixel y + 1); data cols (halfs) 2..257 (pixel x + 2)

__global__ __launch_bounds__(1024) void radon_kernel(
    const float* __restrict__ x, const int* __restrict__ index_p,
    float* __restrict__ out)
{
    __shared__ unsigned sw[ROWS * RWORDS];   // 150,220 B

    const int a = blockIdx.x;        // angle 0..179
    const int n = blockIdx.y;        // batch
    const int tid = threadIdx.x;
    const int c = tid & (W - 1);     // column 0..255
    const int s = tid >> 8;          // r-chunk 0..3 (wave-uniform)

    const float* __restrict__ img = x + (size_t)n * W * W;

    // ---- guard zero-fill (cells disjoint from staged data -> one barrier total) ----
    if (tid < 435) {                       // rows 0,257,258: 3 x 145 words
        const int rr = tid / 145;
        const int w = tid - rr * 145;
        const int row = (rr == 0) ? 0 : (256 + rr);
        sw[row * RWORDS + w] = 0u;
    } else if (tid < 947) {                // col guard words 0,129 rows 1..256
        const int i = tid - 435;
        const int row = 1 + (i >> 1);
        const int w = (i & 1) ? 129 : 0;
        sw[row * RWORDS + w] = 0u;
    }

    // ---- stage image -> LDS fp16 ----
    {
        const float4* img4 = (const float4*)img;
        #pragma unroll
        for (int k = 0; k < 16; ++k) {
            const int g = k * 1024 + tid;
            const int row = (g >> 6) + 1;      // 1..256
            const int m = g & 63;
            const float4 v = img4[g];
            const __half2 h01 = __floats2half2_rn(v.x, v.y);
            const __half2 h23 = __floats2half2_rn(v.z, v.w);
            sw[row * RWORDS + 2 * m + 1] = *(const unsigned*)&h01;  // halfs 4m+2,4m+3
            sw[row * RWORDS + 2 * m + 2] = *(const unsigned*)&h23;
        }
    }
    __syncthreads();

    const int index = *index_p;
    const int seg[6] = {1, 26, 51, 77, 102, 128};
    const int t0 = seg[4 - index];
    const int t1 = seg[4 - index + 1];

    float sa, ca;
    sincosf((float)a * 0.017453292519943295f, &sa, &ca);

    const float xc = ((2.0f * (float)c + 1.0f) * (1.0f / (float)W)) - 1.0f;
    const float bx = fmaf(128.0f * ca, xc, 129.5f);   // +2 x bias (halfs)
    const float by = fmaf(-128.0f * sa, xc, 128.5f);  // +1 y bias (rows)

    const int r1lo = 128 - t1;
    const int r0lo = 128 - t0, r0hi = 127 + t0;
    const int total = 2 * t1;
    const int chunk = (total + SPLIT - 1) / SPLIT;
    const int rs = r1lo + s * chunk;
    const int re = min(rs + chunk, r1lo + total);

#define TAP_BODY                                                              \
        float ix = fmaf(sa, rf, bx);                                          \
        float iy = fmaf(ca, rf, by);                                          \
        ix = __builtin_amdgcn_fmed3f(ix, 1.0f, 258.0f);                       \
        iy = __builtin_amdgcn_fmed3f(iy, 0.0f, 257.0f);                       \
        const float wx = __builtin_amdgcn_fractf(ix);                         \
        const float wy = __builtin_amdgcn_fractf(iy);                         \
        const int x0 = (int)ix;                                               \
        const int y0 = (int)iy;                                               \
        const int wi = y0 * RWORDS + (x0 >> 1);   /* v_mad_u32_u24 */         \
        const unsigned A0 = sw[wi];                                           \
        const unsigned B0 = sw[wi + 1];                                       \
        const unsigned A1 = sw[wi + RWORDS];                                  \
        const unsigned B1 = sw[wi + RWORDS + 1];                              \
        const int sh = (x0 & 1) << 4;                                         \
        const unsigned q0 = __builtin_amdgcn_alignbit(B0, A0, sh);            \
        const unsigned q1 = __builtin_amdgcn_alignbit(B1, A1, sh);            \
        const __half2 h0 = *(const __half2*)&q0;  /* (v00, v01) row y0 */     \
        const __half2 h1 = *(const __half2*)&q1;  /* (v10, v11) row y0+1 */   \
        const __half2 wy2 = __float2half2_rn(wy);                             \
        const __half2 t = __hfma2(wy2, __hsub2(h1, h0), h0);                  \
        const float tl = __low2float(t);                                      \
        const float th = __high2float(t);                                     \
        const float val = fmaf(wx, th - tl, tl);

    float sumA = 0.0f, sumB = 0.0f, sumC = 0.0f;

    // segment A: [rs, min(re, r0lo)) -> outer only
    {
        const int e = min(re, r0lo);
        float rf = (float)rs - 127.5f;
        #pragma unroll 8
        for (int r = rs; r < e; ++r, rf += 1.0f) { TAP_BODY sumA += val; }
    }
    // segment B: [max(rs, r0lo), min(re, r0hi+1)) -> both masks
    {
        const int b = max(rs, r0lo);
        const int e = min(re, r0hi + 1);
        float rf = (float)b - 127.5f;
        #pragma unroll 8
        for (int r = b; r < e; ++r, rf += 1.0f) { TAP_BODY sumB += val; }
    }
    // segment C: [max(rs, r0hi+1), re) -> outer only
    {
        const int b = max(rs, r0hi + 1);
        float rf = (float)b - 127.5f;
        #pragma unroll 8
        for (int r = b; r < re; ++r, rf += 1.0f) { TAP_BODY sumC += val; }
    }
#undef TAP_BODY

    const float sum0 = sumB;
    const float sum1 = sumA + sumB + sumC;

    // ---- reduce partials; reuse sw as scratch ----
    __syncthreads();
    float* red = (float*)sw;                 // 8 KB of 150 KB
    red[(0 * SPLIT + s) * W + c] = sum0;
    red[(1 * SPLIT + s) * W + c] = sum1;
    __syncthreads();

    if (s == 0) {
        const float acc0 = red[0 * W + c] + red[1 * W + c] + red[2 * W + c] + red[3 * W + c];
        const float* r1p = red + SPLIT * W;
        const float acc1 = r1p[0 * W + c] + r1p[1 * W + c] + r1p[2 * W + c] + r1p[3 * W + c];
        out[(((size_t)n * 2 + 0) * W + c) * NA + a] = acc0 * (1.0f / (float)(2 * t0));
        out[(((size_t)n * 2 + 1) * W + c) * NA + a] = acc1 * (1.0f / (float)(2 * t1));
    }
}

extern "C" void kernel_launch(void* const* d_in, const int* in_sizes, int n_in,
                              void* d_out, int out_size, void* d_ws, size_t ws_size,
                              hipStream_t stream) {
    const float* x = (const float*)d_in[0];
    const int* index_p = (const int*)d_in[1];
    float* out = (float*)d_out;
    const int N = in_sizes[0] / (W * W); // 4
    dim3 grid(NA, N);
    radon_kernel<<<grid, 1024, 0, stream>>>(x, index_p, out);
}